// Round 3
// baseline (2404.031 us; speedup 1.0000x reference)
//
#include <hip/hip_runtime.h>
#include <hip/hip_bf16.h>

typedef __hip_bfloat16 bf16;
typedef __attribute__((ext_vector_type(8))) unsigned short ushortx8;

#define HW 65536
#define IMW 256
#define IMH 256

static __device__ __forceinline__ float b2f(bf16 v) { return __bfloat162float(v); }
static __device__ __forceinline__ float u2f(unsigned short u) {
  return __uint_as_float(((unsigned)u) << 16);
}

// ---------------------------------------------------------------------------
// Dtype probe: decide whether external tensors are fp32 or bf16.
// For bf16 N(0,1) data, even 16-bit words have exponent in [0x60,0x90]
// (~100%). For fp32 data, even words are uniform mantissa bits (~19% hit).
// flag = 1 -> fp32 inputs, 0 -> bf16 inputs.
// ---------------------------------------------------------------------------
__global__ void detect_dtype(const unsigned short* __restrict__ w, int* flag) {
  if (threadIdx.x == 0 && blockIdx.x == 0) {
    int cnt = 0;
    for (int k = 0; k < 1024; ++k) {
      unsigned e = (w[2 * k] >> 7) & 0xFF;
      if (e >= 0x60 && e <= 0x90) ++cnt;
    }
    *flag = (cnt < 512) ? 1 : 0;
  }
}

// ---------------------------------------------------------------------------
// Weight conversion: (bf16|fp32) -> fp32 into workspace.
// ---------------------------------------------------------------------------
struct CvtArgs {
  const void* src[20];
  float* dst[20];
  int n[20];
};

__global__ __launch_bounds__(256) void convert_many(CvtArgs a, const int* dtf) {
  bool f32 = *dtf != 0;
  int j = blockIdx.y;
  int i = blockIdx.x * 256 + threadIdx.x;
  if (i < a.n[j]) {
    float v;
    if (f32) v = ((const float*)a.src[j])[i];
    else v = b2f(((const bf16*)a.src[j])[i]);
    a.dst[j][i] = v;
  }
}

// ---------------------------------------------------------------------------
// qk_in build: warp01 | frame[:,1] | warp21 | flow_f[:,1] | flow_b[:,0]
// 100 channels bf16, NCHW. External reads adaptive via template.
// ---------------------------------------------------------------------------
template <typename T>
static __device__ __forceinline__ float ldT(const T* p, size_t i) {
  if (sizeof(T) == 2) return b2f(((const bf16*)p)[i]);
  return ((const float*)p)[i];
}

template <typename T>
static __device__ void warp32(const T* __restrict__ src, float x, float y,
                              bf16* __restrict__ dst) {
  float x0f = floorf(x), y0f = floorf(y);
  float lx = x - x0f, ly = y - y0f;
  int x0 = (int)x0f, y0 = (int)y0f;
  float wt[4] = {(1.f - lx) * (1.f - ly), lx * (1.f - ly), (1.f - lx) * ly, lx * ly};
  int idx[4];
  float w[4];
#pragma unroll
  for (int k = 0; k < 4; ++k) {
    int xi = x0 + (k & 1), yi = y0 + (k >> 1);
    bool v = ((unsigned)xi < IMW) && ((unsigned)yi < IMH);
    idx[k] = v ? (yi * IMW + xi) : 0;
    w[k] = v ? wt[k] : 0.f;
  }
#pragma unroll
  for (int c = 0; c < 32; ++c) {
    float a = 0.f;
#pragma unroll
    for (int k = 0; k < 4; ++k) a = fmaf(w[k], ldT(src, (size_t)c * HW + idx[k]), a);
    dst[(size_t)c * HW] = __float2bfloat16(a);
  }
}

template <typename T>
static __device__ void build_qkin_body(const T* __restrict__ frame,
                                       const T* __restrict__ flowf,
                                       const T* __restrict__ flowb,
                                       bf16* __restrict__ qkin, int pix, int b) {
  int px = pix & (IMW - 1), py = pix >> 8;

  size_t fb = ((size_t)(b * 2 + 0) * 2) * HW + pix;
  float fbx = ldT(flowb, fb), fby = ldT(flowb, fb + HW);
  size_t ff = ((size_t)(b * 2 + 1) * 2) * HW + pix;
  float ffx = ldT(flowf, ff), ffy = ldT(flowf, ff + HW);

  bf16* qb = qkin + (size_t)b * 100 * HW + pix;

  const T* f1 = frame + ((size_t)(b * 3 + 1) * 32) * HW + pix;
#pragma unroll
  for (int c = 0; c < 32; ++c)
    qb[(size_t)(32 + c) * HW] = __float2bfloat16(ldT(f1, (size_t)c * HW));

  qb[(size_t)96 * HW] = __float2bfloat16(ffx);
  qb[(size_t)97 * HW] = __float2bfloat16(ffy);
  qb[(size_t)98 * HW] = __float2bfloat16(fbx);
  qb[(size_t)99 * HW] = __float2bfloat16(fby);

  warp32<T>(frame + ((size_t)(b * 3 + 0) * 32) * HW, (float)px + fbx, (float)py + fby, qb);
  warp32<T>(frame + ((size_t)(b * 3 + 2) * 32) * HW, (float)px + ffx, (float)py + ffy,
            qb + (size_t)64 * HW);
}

__global__ __launch_bounds__(256) void build_qkin(
    const void* __restrict__ frame, const void* __restrict__ flowf,
    const void* __restrict__ flowb, bf16* __restrict__ qkin, const int* dtf) {
  int pix = blockIdx.x * 256 + threadIdx.x;
  int b = blockIdx.y;
  if (*dtf != 0)
    build_qkin_body<float>((const float*)frame, (const float*)flowf,
                           (const float*)flowb, qkin, pix, b);
  else
    build_qkin_body<bf16>((const bf16*)frame, (const bf16*)flowf,
                          (const bf16*)flowb, qkin, pix, b);
}

// ---------------------------------------------------------------------------
// Generic direct 3x3 conv. Block = 16x16 threads, each thread 2x2 pixels,
// 8 output channels per grid-z slice. Input tile via LDS (fp32); weights via
// uniform fp32 scalar loads. pad == DIL (as in reference).
// EXT1: in1 is an external tensor -> dtype per runtime flag; else TIN1.
// Channels >= SPLITC come from in2 (external, dtype per flag).
// RES_MODE: 0 none, 1 fp32 internal residual, 2 external residual (per flag).
// TOUT: bf16 or float (internal buffers only).
// ---------------------------------------------------------------------------
template <int CIN, int DIL, bool LRELU, bool EXT1, typename TIN1, int SPLITC,
          int RES_MODE, typename TOUT, bool PIXMAJOR>
__global__ __launch_bounds__(256) void conv3x3(
    const void* __restrict__ in1_, int in1_cstride, const void* __restrict__ in2_,
    size_t in2_boff, size_t in2_coff, const float* __restrict__ wgt,
    const float* __restrict__ bias, void* __restrict__ out_, int ocb_per_b,
    int out_cstride, int out_coff, const void* __restrict__ res, int res_cstride,
    int res_coff, const int* dtf) {
  constexpr int TS = 32 + 2 * DIL;
  constexpr int VS = 2 + 2 * DIL;
  __shared__ float tile[TS * TS];

  const bool extf32 = *dtf != 0;
  const bool in1f32 = EXT1 ? extf32 : (sizeof(TIN1) == 4);

  int bz = blockIdx.z;
  int b = bz / ocb_per_b;
  int oc0 = (bz % ocb_per_b) * 8;
  int tx = threadIdx.x & 15, ty = threadIdx.x >> 4;
  int px0 = blockIdx.x * 32, py0 = blockIdx.y * 32;

  float acc[8][4] = {};

#pragma unroll 1
  for (int ci = 0; ci < CIN; ++ci) {
    __syncthreads();
    {
      for (int idx = threadIdx.x; idx < TS * TS; idx += 256) {
        int tyy = idx / TS, txx = idx - tyy * TS;
        int gy = py0 + tyy - DIL, gx = px0 + txx - DIL;
        float v = 0.f;
        if ((unsigned)gy < IMH && (unsigned)gx < IMW) {
          size_t p = (size_t)gy * IMW + gx;
          if (SPLITC >= CIN || ci < SPLITC) {
            size_t g = ((size_t)b * in1_cstride + ci) * HW + p;
            if (in1f32) v = ((const float*)in1_)[g];
            else v = b2f(((const bf16*)in1_)[g]);
          } else {
            size_t g = (size_t)b * in2_boff + in2_coff + (size_t)(ci - SPLITC) * HW + p;
            if (extf32) v = ((const float*)in2_)[g];
            else v = b2f(((const bf16*)in2_)[g]);
          }
        }
        tile[idx] = v;
      }
    }
    __syncthreads();

    float vv[VS][VS];
#pragma unroll
    for (int r = 0; r < VS; ++r)
#pragma unroll
      for (int c = 0; c < VS; ++c) vv[r][c] = tile[(2 * ty + r) * TS + (2 * tx + c)];

#pragma unroll
    for (int oc = 0; oc < 8; ++oc) {
      const float* wp = wgt + ((size_t)(oc0 + oc) * CIN + ci) * 9;
      float w9[9];
#pragma unroll
      for (int k = 0; k < 9; ++k) w9[k] = wp[k];
#pragma unroll
      for (int ky = 0; ky < 3; ++ky)
#pragma unroll
        for (int kx = 0; kx < 3; ++kx)
#pragma unroll
          for (int i = 0; i < 2; ++i)
#pragma unroll
            for (int j = 0; j < 2; ++j)
              acc[oc][i * 2 + j] =
                  fmaf(w9[ky * 3 + kx], vv[i + ky * DIL][j + kx * DIL], acc[oc][i * 2 + j]);
    }
  }

  int pyb = py0 + 2 * ty, pxb = px0 + 2 * tx;
#pragma unroll
  for (int oc = 0; oc < 8; ++oc) {
    float bv = bias[oc0 + oc];
#pragma unroll
    for (int i = 0; i < 2; ++i)
#pragma unroll
      for (int j = 0; j < 2; ++j) {
        float r = acc[oc][i * 2 + j] + bv;
        if (LRELU) r = r >= 0.f ? r : 0.1f * r;
        size_t pix = (size_t)(pyb + i) * IMW + (pxb + j);
        if (RES_MODE == 1)
          r += ((const float*)res)[((size_t)b * res_cstride + res_coff + oc0 + oc) * HW + pix];
        if (RES_MODE == 2) {
          size_t ri = ((size_t)b * res_cstride + res_coff + oc0 + oc) * HW + pix;
          if (extf32) r += ((const float*)res)[ri];
          else r += b2f(((const bf16*)res)[ri]);
        }
        size_t oidx = PIXMAJOR ? (((size_t)b * HW + pix) * out_cstride + oc0 + oc)
                               : (((size_t)b * out_cstride + out_coff + oc0 + oc) * HW + pix);
        if (sizeof(TOUT) == 2)
          ((bf16*)out_)[oidx] = __float2bfloat16(r);
        else
          ((float*)out_)[oidx] = r;
      }
  }
}

// ---------------------------------------------------------------------------
// Deformable attention. All operands internal. valp pixel-major bf16
// (b*3+l, pix, 32). off bf16 NCHW (96ch), aw fp32 NCHW (48ch). Out bf16.
// ---------------------------------------------------------------------------
__global__ __launch_bounds__(256) void deform_attn(
    const bf16* __restrict__ valp, const bf16* __restrict__ off,
    const float* __restrict__ aw, bf16* __restrict__ outp) {
  int pix = blockIdx.x * 256 + threadIdx.x;
  int b = blockIdx.y;
  int px = pix & (IMW - 1), py = pix >> 8;
  float refx = ((float)px + 0.5f) * (1.0f / IMW);
  float refy = ((float)py + 0.5f) * (1.0f / IMH);

  for (int hh = 0; hh < 4; ++hh) {
    float wv[12];
    float m = -1e30f;
#pragma unroll
    for (int lp = 0; lp < 12; ++lp) {
      wv[lp] = aw[((size_t)b * 48 + hh * 12 + lp) * HW + pix];
      m = fmaxf(m, wv[lp]);
    }
    float s = 0.f;
#pragma unroll
    for (int lp = 0; lp < 12; ++lp) {
      wv[lp] = __expf(wv[lp] - m);
      s += wv[lp];
    }
    float inv = 1.f / s;

    float acc[8] = {0.f, 0.f, 0.f, 0.f, 0.f, 0.f, 0.f, 0.f};
#pragma unroll 1
    for (int l = 0; l < 3; ++l) {
      const bf16* vbase = valp + ((size_t)(b * 3 + l) * HW) * 32 + hh * 8;
#pragma unroll
      for (int p = 0; p < 4; ++p) {
        int ch = hh * 24 + l * 8 + p * 2;
        float ox = b2f(off[((size_t)b * 96 + ch) * HW + pix]);
        float oy = b2f(off[((size_t)b * 96 + ch + 1) * HW + pix]);
        float x = (refx + ox * (1.0f / IMW)) * (float)IMW - 0.5f;
        float y = (refy + oy * (1.0f / IMH)) * (float)IMH - 0.5f;
        float x0f = floorf(x), y0f = floorf(y);
        float lx = x - x0f, ly = y - y0f;
        int x0 = (int)x0f, y0 = (int)y0f;
        float a = wv[l * 4 + p] * inv;
        float cw[4] = {(1.f - lx) * (1.f - ly) * a, lx * (1.f - ly) * a,
                       (1.f - lx) * ly * a, lx * ly * a};
#pragma unroll
        for (int k = 0; k < 4; ++k) {
          int xi = x0 + (k & 1), yi = y0 + (k >> 1);
          if ((unsigned)xi < IMW && (unsigned)yi < IMH) {
            const ushortx8 u = *(const ushortx8*)(vbase + (size_t)(yi * IMW + xi) * 32);
            float wgt = cw[k];
#pragma unroll
            for (int dd = 0; dd < 8; ++dd) acc[dd] = fmaf(wgt, u2f(u[dd]), acc[dd]);
          }
        }
      }
    }
#pragma unroll
    for (int dd = 0; dd < 8; ++dd)
      outp[((size_t)b * 32 + hh * 8 + dd) * HW + pix] = __float2bfloat16(acc[dd]);
  }
}

// final 1x1 conv + lrelu -> adaptive output dtype
__global__ __launch_bounds__(256) void conv1x1_fu(
    const float* __restrict__ in, const float* __restrict__ wgt,
    const float* __restrict__ bias, void* __restrict__ out, const int* dtf) {
  bool f32 = *dtf != 0;
  int pix = blockIdx.x * 256 + threadIdx.x;
  int b = blockIdx.y;
  float vin[32];
#pragma unroll
  for (int ci = 0; ci < 32; ++ci) vin[ci] = in[((size_t)b * 32 + ci) * HW + pix];
#pragma unroll 1
  for (int oc = 0; oc < 32; ++oc) {
    float a = bias[oc];
#pragma unroll
    for (int ci = 0; ci < 32; ++ci) a = fmaf(wgt[oc * 32 + ci], vin[ci], a);
    a = a >= 0.f ? a : 0.1f * a;
    size_t oi = ((size_t)b * 32 + oc) * HW + pix;
    if (f32) ((float*)out)[oi] = a;
    else ((bf16*)out)[oi] = __float2bfloat16(a);
  }
}

// ---------------------------------------------------------------------------
extern "C" void kernel_launch(void* const* d_in, const int* in_sizes, int n_in,
                              void* d_out, int out_size, void* d_ws, size_t ws_size,
                              hipStream_t stream) {
  (void)in_sizes; (void)n_in; (void)out_size;
  // Total footprint: 25,778,688 floats = 103.1 MB. If ws is smaller, do
  // nothing -> output stays zero (finite absmax ~2.34) as a diagnostic,
  // and we avoid corrupting neighboring allocations.
  if (ws_size < 25778688ull * 4) return;

  const void* frame = d_in[0];
  const void* srcframe = d_in[1];
  const void* flowf = d_in[2];
  const void* flowb = d_in[3];

  float* ws = (float*)d_ws;

  static const int wsz[20] = {86400, 96, 82944, 96, 9216, 32, 82944, 96, 41472, 48,
                              9216, 32, 9216, 32, 18432, 32, 9216, 32, 1024, 32};
  int woff[20];
  {
    int c = 0;
    for (int i = 0; i < 20; ++i) { woff[i] = c; c += wsz[i]; }
  }
  const float* Wqk = ws + woff[0];  const float* bqk = ws + woff[1];
  const float* Wv  = ws + woff[2];  const float* bv  = ws + woff[3];
  const float* Wvp = ws + woff[4];  const float* bvp = ws + woff[5];
  const float* Wof = ws + woff[6];  const float* bof = ws + woff[7];
  const float* Waw = ws + woff[8];  const float* baw = ws + woff[9];
  const float* Wou = ws + woff[10]; const float* bou = ws + woff[11];
  const float* Wfd = ws + woff[12]; const float* bfd = ws + woff[13];
  const float* Wf1 = ws + woff[14]; const float* bf1 = ws + woff[15];
  const float* Wf2 = ws + woff[16]; const float* bf2 = ws + woff[17];
  const float* Wfu = ws + woff[18]; const float* bfu = ws + woff[19];

  int* dtf = (int*)(ws + 350608);  // weights end at 350,608

  // Buffer slots (float offsets), total end = 25,778,688 f.
  bf16* qk_in  = (bf16*)(ws + 350720);
  bf16* Q      = (bf16*)(ws + 6904320);
  bf16* V      = (bf16*)(ws + 13195776);
  bf16* Vp     = (bf16*)(ws + 19487232);
  bf16* offb   = (bf16*)(ws + 350720);
  float* awb   = (float*)(ws + 13195776);
  bf16* attn   = (bf16*)(ws + 6904320);
  bf16* convout= (bf16*)(ws + 6904320 + 2097152);
  float* out1  = (float*)(ws + 19487232);
  bf16* ff1out = (bf16*)(ws + 350720);
  float* out2  = (float*)(ws + 13195776);

  // 0) dtype probe (flag in ws)
  detect_dtype<<<1, 64, 0, stream>>>((const unsigned short*)frame, dtf);

  // 1) weights -> fp32
  {
    CvtArgs ca;
    for (int i = 0; i < 20; ++i) {
      ca.src[i] = d_in[4 + i];
      ca.dst[i] = ws + woff[i];
      ca.n[i] = wsz[i];
    }
    convert_many<<<dim3(338, 20), 256, 0, stream>>>(ca, dtf);
  }

  // 2) qk_in (100ch bf16)
  build_qkin<<<dim3(256, 2), 256, 0, stream>>>(frame, flowf, flowb, qk_in, dtf);

  // 3) qureys = lrelu(conv_qk(qk_in))   100 -> 96, bf16 out
  conv3x3<100, 1, true, false, bf16, 100, 0, bf16, false><<<dim3(8, 8, 24), 256, 0, stream>>>(
      qk_in, 100, nullptr, 0, 0, Wqk, bqk, Q, 12, 96, 0, nullptr, 0, 0, dtf);

  // 4) value = conv_v(frame as (b,96,h,w))  96 -> 96, bf16 out (frame external)
  conv3x3<96, 1, false, true, bf16, 96, 0, bf16, false><<<dim3(8, 8, 24), 256, 0, stream>>>(
      frame, 96, nullptr, 0, 0, Wv, bv, V, 12, 96, 0, nullptr, 0, 0, dtf);

  // 5) val = conv_vp(value as (6,32,h,w)) -> pixel-major bf16 (6, hw, 32)
  conv3x3<32, 1, false, false, bf16, 32, 0, bf16, true><<<dim3(8, 8, 24), 256, 0, stream>>>(
      V, 32, nullptr, 0, 0, Wvp, bvp, Vp, 4, 32, 0, nullptr, 0, 0, dtf);

  // 6) off = conv_off(qureys) 96 -> 96, bf16 out (B1; qk_in dead)
  conv3x3<96, 1, false, false, bf16, 96, 0, bf16, false><<<dim3(8, 8, 24), 256, 0, stream>>>(
      Q, 96, nullptr, 0, 0, Wof, bof, offb, 12, 96, 0, nullptr, 0, 0, dtf);

  // 7) aw = conv_aw(qureys) 96 -> 48, fp32 out (B3; value dead)
  conv3x3<96, 1, false, false, bf16, 96, 0, float, false><<<dim3(8, 8, 12), 256, 0, stream>>>(
      Q, 96, nullptr, 0, 0, Waw, baw, awb, 6, 48, 0, nullptr, 0, 0, dtf);

  // 8) deformable attention -> attn bf16 (B2 head; qureys dead)
  deform_attn<<<dim3(256, 2), 256, 0, stream>>>(Vp, offb, awb, attn);

  // 10) conv_out(attn) 32 -> 32 bf16 (B2 tail)
  conv3x3<32, 1, false, false, bf16, 32, 0, bf16, false><<<dim3(8, 8, 8), 256, 0, stream>>>(
      attn, 32, nullptr, 0, 0, Wou, bou, convout, 4, 32, 0, nullptr, 0, 0, dtf);

  // 11) out1 = conv_ffd(convout) + frame[:,1]  fp32 (B4; Vp dead); frame external res
  conv3x3<32, 1, false, false, bf16, 32, 2, float, false><<<dim3(8, 8, 8), 256, 0, stream>>>(
      convout, 32, nullptr, 0, 0, Wfd, bfd, out1, 4, 32, 0, frame, 96, 32, dtf);

  // 12) ff1 = lrelu(conv dil=2 pad=2 on [out1 | srcframe[:,1]]) -> bf16 (B1)
  conv3x3<64, 2, true, false, float, 32, 0, bf16, false><<<dim3(8, 8, 8), 256, 0, stream>>>(
      out1, 32, srcframe, (size_t)96 * HW, (size_t)32 * HW, Wf1, bf1, ff1out, 4, 32, 0,
      nullptr, 0, 0, dtf);

  // 13) out2 = conv_ff2(ff1out) + out1  fp32 (B3; aw dead)
  conv3x3<32, 1, false, false, bf16, 32, 1, float, false><<<dim3(8, 8, 8), 256, 0, stream>>>(
      ff1out, 32, nullptr, 0, 0, Wf2, bf2, out2, 4, 32, 0, out1, 32, 0, dtf);

  // 14) out = lrelu(conv_fu 1x1(out2)) -> adaptive dtype
  conv1x1_fu<<<dim3(256, 2), 256, 0, stream>>>(out2, Wfu, bfu, d_out, dtf);
}

// Round 4
// 865.580 us; speedup vs baseline: 2.7774x; 2.7774x over previous
//
#include <hip/hip_runtime.h>
#include <hip/hip_bf16.h>

typedef __hip_bfloat16 bf16;
typedef __attribute__((ext_vector_type(8))) short short8;
typedef __attribute__((ext_vector_type(4))) float f32x4;
typedef __attribute__((ext_vector_type(8))) unsigned short ushortx8;

#define HW 65536
#define IMW 256
#define IMH 256

static __device__ __forceinline__ float b2f(bf16 v) { return __bfloat162float(v); }
static __device__ __forceinline__ float u2f(unsigned short u) {
  return __uint_as_float(((unsigned)u) << 16);
}
static __device__ __forceinline__ unsigned short f2bu(float x) {
  bf16 h = __float2bfloat16(x);
  return *reinterpret_cast<unsigned short*>(&h);
}

// ---------------------------------------------------------------------------
// Weight prep: fp32 [oc][ci][3][3] -> bf16 [tap][oc][KPAD] (K zero-padded).
// ---------------------------------------------------------------------------
struct PrepArgs {
  const float* src[9];
  unsigned short* dst[9];
  int OC[9], CIN[9], KPAD[9];
};

__global__ __launch_bounds__(256) void prep_weights(PrepArgs a) {
  int j = blockIdx.y;
  int n = blockIdx.x * 256 + threadIdx.x;
  int OC = a.OC[j], CIN = a.CIN[j], KPAD = a.KPAD[j];
  int tot = 9 * OC * KPAD;
  if (n >= tot) return;
  int t = n / (OC * KPAD);
  int rem = n - t * OC * KPAD;
  int oc = rem / KPAD;
  int k = rem - oc * KPAD;
  float v = (k < CIN) ? a.src[j][(size_t)(oc * CIN + k) * 9 + t] : 0.f;
  a.dst[j][n] = f2bu(v);
}

// ---------------------------------------------------------------------------
// qk_in build (fp32 inputs -> bf16 NCHW 100ch):
// warp01 | frame[:,1] | warp21 | flow_f[:,1] | flow_b[:,0]
// ---------------------------------------------------------------------------
static __device__ void warp32(const float* __restrict__ src, float x, float y,
                              unsigned short* __restrict__ dst) {
  float x0f = floorf(x), y0f = floorf(y);
  float lx = x - x0f, ly = y - y0f;
  int x0 = (int)x0f, y0 = (int)y0f;
  float wt[4] = {(1.f - lx) * (1.f - ly), lx * (1.f - ly), (1.f - lx) * ly, lx * ly};
  int idx[4];
  float w[4];
#pragma unroll
  for (int k = 0; k < 4; ++k) {
    int xi = x0 + (k & 1), yi = y0 + (k >> 1);
    bool v = ((unsigned)xi < IMW) && ((unsigned)yi < IMH);
    idx[k] = v ? (yi * IMW + xi) : 0;
    w[k] = v ? wt[k] : 0.f;
  }
#pragma unroll
  for (int c = 0; c < 32; ++c) {
    float a = 0.f;
#pragma unroll
    for (int k = 0; k < 4; ++k) a = fmaf(w[k], src[(size_t)c * HW + idx[k]], a);
    dst[(size_t)c * HW] = f2bu(a);
  }
}

__global__ __launch_bounds__(256) void build_qkin(
    const float* __restrict__ frame, const float* __restrict__ flowf,
    const float* __restrict__ flowb, unsigned short* __restrict__ qkin) {
  int pix = blockIdx.x * 256 + threadIdx.x;
  int b = blockIdx.y;
  int px = pix & (IMW - 1), py = pix >> 8;

  size_t fb = ((size_t)(b * 2 + 0) * 2) * HW + pix;
  float fbx = flowb[fb], fby = flowb[fb + HW];
  size_t ff = ((size_t)(b * 2 + 1) * 2) * HW + pix;
  float ffx = flowf[ff], ffy = flowf[ff + HW];

  unsigned short* qb = qkin + (size_t)b * 100 * HW + pix;

  const float* f1 = frame + ((size_t)(b * 3 + 1) * 32) * HW + pix;
#pragma unroll
  for (int c = 0; c < 32; ++c) qb[(size_t)(32 + c) * HW] = f2bu(f1[(size_t)c * HW]);

  qb[(size_t)96 * HW] = f2bu(ffx);
  qb[(size_t)97 * HW] = f2bu(ffy);
  qb[(size_t)98 * HW] = f2bu(fbx);
  qb[(size_t)99 * HW] = f2bu(fby);

  warp32(frame + ((size_t)(b * 3 + 0) * 32) * HW, (float)px + fbx, (float)py + fby, qb);
  warp32(frame + ((size_t)(b * 3 + 2) * 32) * HW, (float)px + ffx, (float)py + ffy,
         qb + (size_t)64 * HW);
}

// ---------------------------------------------------------------------------
// MFMA implicit-GEMM 3x3 conv (pad == DIL).
// Block: 256 threads = 4 waves; tile = 16 cols x 8 rows of output pixels.
// Wave wv computes rows {2wv, 2wv+1} for all OC/16 oc-groups.
// LDS: input tile as [pos=(row,col)][ci] bf16, ci-contiguous (16B frags).
// A (weights): bf16 [tap][oc][KPAD] from global (L2-resident).
// mfma_f32_16x16x32_bf16: A[m=lane&15][k=q*8+j], B[k=q*8+j][n=lane&15],
// C/D: col(n)=lane&15, row(m)=q*4+reg.   (layouts per cdna_hip_programming §3)
// INMODE: 0 = bf16 NCHW in1; 1 = fp32 NCHW in1; 2 = fp32 split (in1 32ch + in2)
// RES: 0 none, 1 fp32 NCHW residual.  OUTMODE: 0 bf16 NCHW, 1 f32 NCHW,
// 2 bf16 pixel-major [b][pix][32].
// ---------------------------------------------------------------------------
template <int CIN, int KPAD, int DIL, int OC, int INMODE, int RES, int OUTMODE,
          bool LRELU>
__global__ __launch_bounds__(256) void conv3x3_mfma(
    const void* __restrict__ in1, int in1_cst, const float* __restrict__ in2,
    size_t in2_boff, const unsigned short* __restrict__ W2,
    const float* __restrict__ bias, void* __restrict__ out, int out_cst,
    const float* __restrict__ res, int res_cst, int res_coff) {
  constexpr int COLS = 16 + 2 * DIL;
  constexpr int ROWS = 8 + 2 * DIL;
  constexpr int CIPAD = KPAD + 8;  // mult of 8 -> 16B-aligned frags, even banks
  constexpr int G = OC / 16;
  __shared__ short lds[ROWS * COLS * CIPAD];

  const int b = blockIdx.z;
  const int px0 = blockIdx.x * 16, py0 = blockIdx.y * 8;

  // ---- stage input tile (bf16) into LDS -------------------------------
  for (int pos = threadIdx.x; pos < ROWS * COLS; pos += 256) {
    int row = pos / COLS, col = pos - row * COLS;
    int gy = py0 + row - DIL, gx = px0 + col - DIL;
    bool ok = ((unsigned)gy < IMH) && ((unsigned)gx < IMW);
    size_t gp = (size_t)gy * IMW + gx;
    short* dst = &lds[pos * CIPAD];
    if (INMODE == 0) {
      const unsigned short* s =
          (const unsigned short*)in1 + ((size_t)b * in1_cst) * HW + gp;
#pragma unroll 4
      for (int ci = 0; ci < KPAD; ci += 2) {
        unsigned u = 0;
        if (ok) {
          unsigned lo = (ci < CIN) ? s[(size_t)ci * HW] : 0u;
          unsigned hi = (ci + 1 < CIN) ? s[(size_t)(ci + 1) * HW] : 0u;
          u = lo | (hi << 16);
        }
        *(unsigned*)&dst[ci] = u;
      }
    } else if (INMODE == 1) {
      const float* s = (const float*)in1 + ((size_t)b * in1_cst) * HW + gp;
#pragma unroll 4
      for (int ci = 0; ci < KPAD; ci += 2) {
        unsigned u = 0;
        if (ok) {
          float lo = (ci < CIN) ? s[(size_t)ci * HW] : 0.f;
          float hi = (ci + 1 < CIN) ? s[(size_t)(ci + 1) * HW] : 0.f;
          u = (unsigned)f2bu(lo) | ((unsigned)f2bu(hi) << 16);
        }
        *(unsigned*)&dst[ci] = u;
      }
    } else {
      const float* s1 = (const float*)in1 + ((size_t)b * in1_cst) * HW + gp;
      const float* s2 = in2 + (size_t)b * in2_boff + gp;
#pragma unroll 4
      for (int ci = 0; ci < KPAD; ci += 2) {
        unsigned u = 0;
        if (ok) {
          float lo = (ci < 32) ? s1[(size_t)ci * HW] : s2[(size_t)(ci - 32) * HW];
          float hi =
              (ci + 1 < 32) ? s1[(size_t)(ci + 1) * HW] : s2[(size_t)(ci + 1 - 32) * HW];
          u = (unsigned)f2bu(lo) | ((unsigned)f2bu(hi) << 16);
        }
        *(unsigned*)&dst[ci] = u;
      }
    }
  }
  __syncthreads();

  // ---- MFMA K-loop ----------------------------------------------------
  const int lane = threadIdx.x & 63;
  const int wv = threadIdx.x >> 6;
  const int m = lane & 15, q = lane >> 4;

  f32x4 acc[G][2];
#pragma unroll
  for (int g = 0; g < G; ++g) {
    acc[g][0] = 0.f;
    acc[g][1] = 0.f;
  }

  const unsigned short* Wl = W2 + (size_t)m * KPAD + q * 8;

#pragma unroll
  for (int t = 0; t < 9; ++t) {
    const int dy = t / 3 - 1, dx = t - (t / 3) * 3 - 1;
#pragma unroll
    for (int kc = 0; kc < KPAD / 32; ++kc) {
      short8 bfr[2];
#pragma unroll
      for (int r = 0; r < 2; ++r) {
        int rr = 2 * wv + r + DIL + dy * DIL;
        int cc = m + DIL + dx * DIL;
        bfr[r] = *(const short8*)&lds[(rr * COLS + cc) * CIPAD + kc * 32 + q * 8];
      }
#pragma unroll
      for (int g = 0; g < G; ++g) {
        short8 af = *(const short8*)(Wl + (size_t)((t * OC + g * 16) * KPAD + kc * 32));
#pragma unroll
        for (int r = 0; r < 2; ++r)
          acc[g][r] = __builtin_amdgcn_mfma_f32_16x16x32_bf16(af, bfr[r], acc[g][r], 0, 0, 0);
      }
    }
  }

  // ---- epilogue -------------------------------------------------------
#pragma unroll
  for (int g = 0; g < G; ++g) {
    f32x4 bb = *(const f32x4*)&bias[g * 16 + q * 4];
#pragma unroll
    for (int r = 0; r < 2; ++r) {
      int py = py0 + 2 * wv + r;
      int px = px0 + m;
      size_t pix = (size_t)py * IMW + px;
      if (OUTMODE == 2) {
        unsigned short pk[4];
#pragma unroll
        for (int e = 0; e < 4; ++e) {
          float v = acc[g][r][e] + bb[e];
          if (LRELU) v = v >= 0.f ? v : 0.1f * v;
          pk[e] = f2bu(v);
        }
        uint2 w;
        w.x = (unsigned)pk[0] | ((unsigned)pk[1] << 16);
        w.y = (unsigned)pk[2] | ((unsigned)pk[3] << 16);
        *(uint2*)&((unsigned short*)out)[((size_t)b * HW + pix) * 32 + g * 16 + q * 4] = w;
      } else {
#pragma unroll
        for (int e = 0; e < 4; ++e) {
          int oc = g * 16 + q * 4 + e;
          float v = acc[g][r][e] + bb[e];
          if (LRELU) v = v >= 0.f ? v : 0.1f * v;
          if (RES == 1)
            v += res[((size_t)b * res_cst + res_coff + oc) * HW + pix];
          size_t oi = ((size_t)b * out_cst + oc) * HW + pix;
          if (OUTMODE == 0)
            ((unsigned short*)out)[oi] = f2bu(v);
          else
            ((float*)out)[oi] = v;
        }
      }
    }
  }
}

// ---------------------------------------------------------------------------
// Deformable attention. valp pixel-major bf16 (b*3+l, pix, 32). off bf16 NCHW
// (96ch), aw fp32 NCHW (48ch). Out attn bf16 NCHW (32ch).
// ---------------------------------------------------------------------------
__global__ __launch_bounds__(256) void deform_attn(
    const unsigned short* __restrict__ valp, const unsigned short* __restrict__ off,
    const float* __restrict__ aw, unsigned short* __restrict__ outp) {
  int pix = blockIdx.x * 256 + threadIdx.x;
  int b = blockIdx.y;
  int px = pix & (IMW - 1), py = pix >> 8;
  float refx = ((float)px + 0.5f) * (1.0f / IMW);
  float refy = ((float)py + 0.5f) * (1.0f / IMH);

  for (int hh = 0; hh < 4; ++hh) {
    float wv[12];
    float m = -1e30f;
#pragma unroll
    for (int lp = 0; lp < 12; ++lp) {
      wv[lp] = aw[((size_t)b * 48 + hh * 12 + lp) * HW + pix];
      m = fmaxf(m, wv[lp]);
    }
    float s = 0.f;
#pragma unroll
    for (int lp = 0; lp < 12; ++lp) {
      wv[lp] = __expf(wv[lp] - m);
      s += wv[lp];
    }
    float inv = 1.f / s;

    float acc[8] = {0.f, 0.f, 0.f, 0.f, 0.f, 0.f, 0.f, 0.f};
#pragma unroll 1
    for (int l = 0; l < 3; ++l) {
      const unsigned short* vbase = valp + ((size_t)(b * 3 + l) * HW) * 32 + hh * 8;
#pragma unroll
      for (int p = 0; p < 4; ++p) {
        int ch = hh * 24 + l * 8 + p * 2;
        float ox = u2f(off[((size_t)b * 96 + ch) * HW + pix]);
        float oy = u2f(off[((size_t)b * 96 + ch + 1) * HW + pix]);
        float x = (refx + ox * (1.0f / IMW)) * (float)IMW - 0.5f;
        float y = (refy + oy * (1.0f / IMH)) * (float)IMH - 0.5f;
        float x0f = floorf(x), y0f = floorf(y);
        float lx = x - x0f, ly = y - y0f;
        int x0 = (int)x0f, y0 = (int)y0f;
        float a = wv[l * 4 + p] * inv;
        float cw[4] = {(1.f - lx) * (1.f - ly) * a, lx * (1.f - ly) * a,
                       (1.f - lx) * ly * a, lx * ly * a};
#pragma unroll
        for (int k = 0; k < 4; ++k) {
          int xi = x0 + (k & 1), yi = y0 + (k >> 1);
          if ((unsigned)xi < IMW && (unsigned)yi < IMH) {
            const ushortx8 u = *(const ushortx8*)(vbase + (size_t)(yi * IMW + xi) * 32);
            float wgt = cw[k];
#pragma unroll
            for (int dd = 0; dd < 8; ++dd) acc[dd] = fmaf(wgt, u2f(u[dd]), acc[dd]);
          }
        }
      }
    }
#pragma unroll
    for (int dd = 0; dd < 8; ++dd)
      outp[((size_t)b * 32 + hh * 8 + dd) * HW + pix] = f2bu(acc[dd]);
  }
}

// final 1x1 conv + lrelu -> fp32 out
__global__ __launch_bounds__(256) void conv1x1_fu(
    const float* __restrict__ in, const float* __restrict__ wgt,
    const float* __restrict__ bias, float* __restrict__ out) {
  int pix = blockIdx.x * 256 + threadIdx.x;
  int b = blockIdx.y;
  float vin[32];
#pragma unroll
  for (int ci = 0; ci < 32; ++ci) vin[ci] = in[((size_t)b * 32 + ci) * HW + pix];
#pragma unroll 1
  for (int oc = 0; oc < 32; ++oc) {
    float a = bias[oc];
#pragma unroll
    for (int ci = 0; ci < 32; ++ci) a = fmaf(wgt[oc * 32 + ci], vin[ci], a);
    a = a >= 0.f ? a : 0.1f * a;
    out[((size_t)b * 32 + oc) * HW + pix] = a;
  }
}

// ---------------------------------------------------------------------------
extern "C" void kernel_launch(void* const* d_in, const int* in_sizes, int n_in,
                              void* d_out, int out_size, void* d_ws, size_t ws_size,
                              hipStream_t stream) {
  (void)in_sizes; (void)n_in; (void)out_size;
  // Footprint: 25,614,592 floats = 102.5 MB (round-3's 103.1 MB fit).
  if (ws_size < 25614592ull * 4) return;

  const float* frame = (const float*)d_in[0];
  const float* srcframe = (const float*)d_in[1];
  const float* flowf = (const float*)d_in[2];
  const float* flowb = (const float*)d_in[3];

  float* ws = (float*)d_ws;
  unsigned short* wsu = (unsigned short*)d_ws;

  // W2 (bf16) offsets in shorts: qk,v,vp,off,aw,out,ffd,ff1,ff2
  static const int w2off[9] = {0,      110592, 193536, 202752, 285696,
                               327168, 336384, 345600, 364032};  // end 373248
  const unsigned short* Wqk2 = wsu + w2off[0];
  const unsigned short* Wv2 = wsu + w2off[1];
  const unsigned short* Wvp2 = wsu + w2off[2];
  const unsigned short* Wof2 = wsu + w2off[3];
  const unsigned short* Waw2 = wsu + w2off[4];
  const unsigned short* Wou2 = wsu + w2off[5];
  const unsigned short* Wfd2 = wsu + w2off[6];
  const unsigned short* Wf12 = wsu + w2off[7];
  const unsigned short* Wf22 = wsu + w2off[8];

  // Activation slots (float offsets), W2 region = 186,624 floats:
  //  A @  186,624 (6,553,600 f): qk_in -> offb -> ff1out     (bf16)
  //  B @6,740,224 (6,291,456 f): Q -> attn(2M) + convout(2M) (bf16)
  //  C @13,031,680(6,291,456 f): V (bf16) -> awb (f32) -> out2 (f32)
  //  D @19,323,136(6,291,456 f): Vp (bf16 pixmajor) -> out1 (f32)
  unsigned short* qk_in = (unsigned short*)(ws + 186624);
  unsigned short* Q = (unsigned short*)(ws + 6740224);
  unsigned short* V = (unsigned short*)(ws + 13031680);
  unsigned short* Vp = (unsigned short*)(ws + 19323136);
  unsigned short* offb = (unsigned short*)(ws + 186624);
  float* awb = (float*)(ws + 13031680);
  unsigned short* attn = (unsigned short*)(ws + 6740224);
  unsigned short* convout = (unsigned short*)(ws + 6740224 + 2097152);
  float* out1 = (float*)(ws + 19323136);
  unsigned short* ff1out = (unsigned short*)(ws + 186624);
  float* out2 = (float*)(ws + 13031680);

  // 1) weight prep (fp32 -> bf16 [tap][oc][KPAD])
  {
    PrepArgs pa;
    static const int srcidx[9] = {4, 6, 8, 10, 12, 14, 16, 18, 20};
    static const int OCs[9] = {96, 96, 32, 96, 48, 32, 32, 32, 32};
    static const int CINs[9] = {100, 96, 32, 96, 96, 32, 32, 64, 32};
    static const int KPADs[9] = {128, 96, 32, 96, 96, 32, 32, 64, 32};
    for (int i = 0; i < 9; ++i) {
      pa.src[i] = (const float*)d_in[srcidx[i]];
      pa.dst[i] = wsu + w2off[i];
      pa.OC[i] = OCs[i];
      pa.CIN[i] = CINs[i];
      pa.KPAD[i] = KPADs[i];
    }
    prep_weights<<<dim3(432, 9), 256, 0, stream>>>(pa);
  }

  // 2) qk_in (100ch bf16)
  build_qkin<<<dim3(256, 2), 256, 0, stream>>>(frame, flowf, flowb, qk_in);

  dim3 cgrid(16, 32, 2);

  // 3) qureys = lrelu(conv_qk(qk_in))  100->96 bf16
  conv3x3_mfma<100, 128, 1, 96, 0, 0, 0, true><<<cgrid, 256, 0, stream>>>(
      qk_in, 100, nullptr, 0, Wqk2, (const float*)d_in[5], Q, 96, nullptr, 0, 0);

  // 4) value = conv_v(frame (b,96,h,w) fp32) 96->96 bf16
  conv3x3_mfma<96, 96, 1, 96, 1, 0, 0, false><<<cgrid, 256, 0, stream>>>(
      frame, 96, nullptr, 0, Wv2, (const float*)d_in[7], V, 96, nullptr, 0, 0);

  // 5) val = conv_vp(value as (6,32,h,w)) -> pixel-major bf16
  conv3x3_mfma<32, 32, 1, 32, 0, 0, 2, false><<<dim3(16, 32, 6), 256, 0, stream>>>(
      V, 32, nullptr, 0, Wvp2, (const float*)d_in[9], Vp, 32, nullptr, 0, 0);

  // 6) off = conv_off(qureys) 96->96 bf16 (slot A; qk_in dead)
  conv3x3_mfma<96, 96, 1, 96, 0, 0, 0, false><<<cgrid, 256, 0, stream>>>(
      Q, 96, nullptr, 0, Wof2, (const float*)d_in[11], offb, 96, nullptr, 0, 0);

  // 7) aw = conv_aw(qureys) 96->48 fp32 (slot C; value dead)
  conv3x3_mfma<96, 96, 1, 48, 0, 0, 1, false><<<cgrid, 256, 0, stream>>>(
      Q, 96, nullptr, 0, Waw2, (const float*)d_in[13], awb, 48, nullptr, 0, 0);

  // 8) deformable attention -> attn bf16 (slot B head; qureys dead)
  deform_attn<<<dim3(256, 2), 256, 0, stream>>>(Vp, offb, awb, attn);

  // 9) conv_out(attn) 32->32 bf16 (slot B tail)
  conv3x3_mfma<32, 32, 1, 32, 0, 0, 0, false><<<cgrid, 256, 0, stream>>>(
      attn, 32, nullptr, 0, Wou2, (const float*)d_in[15], convout, 32, nullptr, 0, 0);

  // 10) out1 = conv_ffd(convout) + frame[:,1]  fp32 (slot D; Vp dead)
  conv3x3_mfma<32, 32, 1, 32, 0, 1, 1, false><<<cgrid, 256, 0, stream>>>(
      convout, 32, nullptr, 0, Wfd2, (const float*)d_in[17], out1, 32, frame, 96, 32);

  // 11) ff1 = lrelu(conv dil=2 on [out1 | srcframe[:,1]]) -> bf16 (slot A)
  conv3x3_mfma<64, 64, 2, 32, 2, 0, 0, true><<<cgrid, 256, 0, stream>>>(
      out1, 32, srcframe + (size_t)32 * HW, (size_t)96 * HW, Wf12,
      (const float*)d_in[19], ff1out, 32, nullptr, 0, 0);

  // 12) out2 = conv_ff2(ff1out) + out1  fp32 (slot C; awb dead)
  conv3x3_mfma<32, 32, 1, 32, 0, 1, 1, false><<<cgrid, 256, 0, stream>>>(
      ff1out, 32, nullptr, 0, Wf22, (const float*)d_in[21], out2, 32, out1, 32, 0);

  // 13) out = lrelu(conv_fu 1x1(out2)) -> fp32 d_out
  conv1x1_fu<<<dim3(256, 2), 256, 0, stream>>>(out2, (const float*)d_in[22],
                                               (const float*)d_in[23], (float*)d_out);
}

// Round 5
// 697.481 us; speedup vs baseline: 3.4467x; 1.2410x over previous
//
#include <hip/hip_runtime.h>
#include <hip/hip_bf16.h>

typedef __hip_bfloat16 bf16;
typedef unsigned short us;
typedef __attribute__((ext_vector_type(8))) short short8;
typedef __attribute__((ext_vector_type(8))) unsigned short ushortx8;
typedef __attribute__((ext_vector_type(4))) float f32x4;

#define HW 65536
#define IMW 256
#define IMH 256

static __device__ __forceinline__ float u2f(us u) {
  return __uint_as_float(((unsigned)u) << 16);
}
static __device__ __forceinline__ us f2bu(float x) {
  bf16 h = __float2bfloat16(x);
  return *reinterpret_cast<us*>(&h);
}
static __device__ __forceinline__ unsigned pk2(float a, float b) {
  return (unsigned)f2bu(a) | ((unsigned)f2bu(b) << 16);
}

// ---------------------------------------------------------------------------
// Weight prep: fp32 [oc][ci][3][3] -> bf16 [tap][oc][KPAD] (K zero-padded).
// ---------------------------------------------------------------------------
struct PrepArgs {
  const float* src[9];
  us* dst[9];
  int OC[9], CIN[9], KPAD[9];
};

__global__ __launch_bounds__(256) void prep_weights(PrepArgs a) {
  int j = blockIdx.y;
  int n = blockIdx.x * 256 + threadIdx.x;
  int OC = a.OC[j], CIN = a.CIN[j], KPAD = a.KPAD[j];
  int tot = 9 * OC * KPAD;
  if (n >= tot) return;
  int t = n / (OC * KPAD);
  int rem = n - t * OC * KPAD;
  int oc = rem / KPAD;
  int k = rem - oc * KPAD;
  float v = (k < CIN) ? a.src[j][(size_t)(oc * CIN + k) * 9 + t] : 0.f;
  a.dst[j][n] = f2bu(v);
}

// ---------------------------------------------------------------------------
// frame fp32 NCHW [b][96][HW] -> NHWC bf16 [b][HW][96]
// ---------------------------------------------------------------------------
__global__ __launch_bounds__(256) void frame_to_nhwc(const float* __restrict__ frame,
                                                     unsigned* __restrict__ fn) {
  int pix = blockIdx.x * 256 + threadIdx.x;
  int b = blockIdx.y;
  const float* s = frame + (size_t)b * 96 * HW + pix;
  unsigned u[48];
#pragma unroll
  for (int j = 0; j < 48; ++j)
    u[j] = pk2(s[(size_t)(2 * j) * HW], s[(size_t)(2 * j + 1) * HW]);
  unsigned* d = fn + ((size_t)b * HW + pix) * 48;
#pragma unroll
  for (int j = 0; j < 12; ++j) {
    uint4 w;
    w.x = u[4 * j]; w.y = u[4 * j + 1]; w.z = u[4 * j + 2]; w.w = u[4 * j + 3];
    *(uint4*)&d[4 * j] = w;
  }
}

// ---------------------------------------------------------------------------
// qk_in build from NHWC frame: warp01 | frame[:,1] | warp21 | flows
// -> qk NHWC bf16 [b][HW][100]  (stored via uint2, 8B aligned)
// ---------------------------------------------------------------------------
static __device__ void warp_nhwc(const us* __restrict__ fn, size_t bbase, int coff,
                                 float x, float y, unsigned* uo) {
  float x0f = floorf(x), y0f = floorf(y);
  float lx = x - x0f, ly = y - y0f;
  int x0 = (int)x0f, y0 = (int)y0f;
  float wt[4] = {(1.f - lx) * (1.f - ly), lx * (1.f - ly), (1.f - lx) * ly, lx * ly};
  float acc[32] = {};
#pragma unroll
  for (int k = 0; k < 4; ++k) {
    int xi = x0 + (k & 1), yi = y0 + (k >> 1);
    if ((unsigned)xi < IMW && (unsigned)yi < IMH) {
      const ushortx8* s =
          (const ushortx8*)(fn + (bbase + (size_t)yi * IMW + xi) * 96 + coff);
      float w = wt[k];
#pragma unroll
      for (int cj = 0; cj < 4; ++cj) {
        ushortx8 vv = s[cj];
#pragma unroll
        for (int e = 0; e < 8; ++e)
          acc[cj * 8 + e] = fmaf(w, u2f(vv[e]), acc[cj * 8 + e]);
      }
    }
  }
#pragma unroll
  for (int j = 0; j < 16; ++j) uo[j] = pk2(acc[2 * j], acc[2 * j + 1]);
}

__global__ __launch_bounds__(256) void build_qkin(
    const us* __restrict__ fn, const float* __restrict__ flowf,
    const float* __restrict__ flowb, unsigned* __restrict__ qk) {
  int pix = blockIdx.x * 256 + threadIdx.x;
  int b = blockIdx.y;
  int px = pix & 255, py = pix >> 8;

  float fbx = flowb[((size_t)(b * 2 + 0) * 2 + 0) * HW + pix];
  float fby = flowb[((size_t)(b * 2 + 0) * 2 + 1) * HW + pix];
  float ffx = flowf[((size_t)(b * 2 + 1) * 2 + 0) * HW + pix];
  float ffy = flowf[((size_t)(b * 2 + 1) * 2 + 1) * HW + pix];

  unsigned u[50];

  // ch32..63 straight copy of frame[:,1] (fn ch32..63)
  {
    const unsigned* s = (const unsigned*)(fn + ((size_t)b * HW + pix) * 96);
#pragma unroll
    for (int j = 0; j < 16; ++j) u[16 + j] = s[16 + j];
  }
  // flows -> ch96..99
  u[48] = pk2(ffx, ffy);
  u[49] = pk2(fbx, fby);

  warp_nhwc(fn, (size_t)b * HW, 0, (float)px + fbx, (float)py + fby, &u[0]);
  warp_nhwc(fn, (size_t)b * HW, 64, (float)px + ffx, (float)py + ffy, &u[32]);

  unsigned* qb = qk + ((size_t)b * HW + pix) * 50;
#pragma unroll
  for (int j = 0; j < 25; ++j) {
    uint2 t;
    t.x = u[2 * j];
    t.y = u[2 * j + 1];
    *(uint2*)(qb + 2 * j) = t;
  }
}

// ---------------------------------------------------------------------------
// MFMA implicit-GEMM 3x3 conv, NHWC bf16 input.
// Block 256 thr = 4 waves; tile 16 cols x 8 rows; wave = 2 rows, all oc.
// CINB: real channel bytes/pixel; CST: global cstride (shorts); KPAD: K (mult 32).
// ZDIV/CSUB: input batch split (vp: z -> bin=z/3, coff=(z%3)*32).
// RES: 0 none, 1 f32 NHWC (res_cst), 2 fp32 NCHW (res_cst,res_coff).
// OUTMODE: 0 bf16 NHWC (out_cst,out_coff), 2 f32 NHWC (out_cst), 3 = 0 + f32 NHWC-32 to outB.
// ---------------------------------------------------------------------------
template <int CINB, int CST, int KPAD, int DIL, int OC, int ZDIV, int CSUB,
          int RES, int OUTMODE, bool LRELU>
__global__ __launch_bounds__(256) void conv3x3_mfma(
    const us* __restrict__ in, const us* __restrict__ W2,
    const float* __restrict__ bias, void* __restrict__ out, int out_cst,
    int out_coff, float* __restrict__ outB, const float* __restrict__ res,
    int res_cst, int res_coff) {
  constexpr int COLS = 16 + 2 * DIL;
  constexpr int ROWS = 8 + 2 * DIL;
  constexpr int HALO = ROWS * COLS;
  constexpr int CIPAD = KPAD + 8;
  constexpr int CH = KPAD / 8;
  constexpr int G = OC / 16;
  __shared__ alignas(16) short lds[HALO * CIPAD];

  const int z = blockIdx.z;
  const int bin = z / ZDIV;
  const int coff = (z % ZDIV) * CSUB;
  const int px0 = blockIdx.x * 16, py0 = blockIdx.y * 8;

  // ---- stage NHWC tile into LDS [pos][ci] ----------------------------
  for (int c = threadIdx.x; c < HALO * CH; c += 256) {
    int p = c / CH, cb = c - p * CH;
    int row = p / COLS, col = p - row * COLS;
    int gy = py0 + row - DIL, gx = px0 + col - DIL;
    bool ok = ((unsigned)gy < IMH) && ((unsigned)gx < IMW);
    int lo = cb * 16;
    if (CINB % 16 == 0) {
      short8 v = (short8)0;
      if (ok && lo + 16 <= CINB)
        v = *(const short8*)(in + ((size_t)bin * HW + (size_t)gy * IMW + gx) * CST +
                             coff + cb * 8);
      *(short8*)&lds[p * CIPAD + cb * 8] = v;
    } else {
      uint2 p0; p0.x = 0; p0.y = 0;
      uint2 p1; p1.x = 0; p1.y = 0;
      if (ok) {
        const us* g =
            in + ((size_t)bin * HW + (size_t)gy * IMW + gx) * CST + coff + cb * 8;
        if (lo + 8 <= CINB) p0 = *(const uint2*)g;
        if (lo + 16 <= CINB) p1 = *(const uint2*)(g + 4);
      }
      *(uint2*)&lds[p * CIPAD + cb * 8] = p0;
      *(uint2*)&lds[p * CIPAD + cb * 8 + 4] = p1;
    }
  }
  __syncthreads();

  // ---- MFMA K-loop ----------------------------------------------------
  const int lane = threadIdx.x & 63;
  const int wv = threadIdx.x >> 6;
  const int m = lane & 15, q = lane >> 4;

  f32x4 acc[G][2];
#pragma unroll
  for (int g = 0; g < G; ++g) {
    acc[g][0] = 0.f;
    acc[g][1] = 0.f;
  }

  const us* Wl = W2 + (size_t)m * KPAD + q * 8;

#pragma unroll
  for (int t = 0; t < 9; ++t) {
    const int dy = t / 3 - 1, dx = t - (t / 3) * 3 - 1;
#pragma unroll
    for (int kc = 0; kc < KPAD / 32; ++kc) {
      short8 bfr[2];
#pragma unroll
      for (int r = 0; r < 2; ++r) {
        int rr = 2 * wv + r + DIL + dy * DIL;
        int cc = m + DIL + dx * DIL;
        bfr[r] = *(const short8*)&lds[(rr * COLS + cc) * CIPAD + kc * 32 + q * 8];
      }
#pragma unroll
      for (int g = 0; g < G; ++g) {
        short8 af = *(const short8*)(Wl + (size_t)((t * OC + g * 16) * KPAD + kc * 32));
#pragma unroll
        for (int r = 0; r < 2; ++r)
          acc[g][r] =
              __builtin_amdgcn_mfma_f32_16x16x32_bf16(af, bfr[r], acc[g][r], 0, 0, 0);
      }
    }
  }

  // ---- epilogue -------------------------------------------------------
#pragma unroll
  for (int g = 0; g < G; ++g) {
    f32x4 bb = *(const f32x4*)&bias[g * 16 + q * 4];
#pragma unroll
    for (int r = 0; r < 2; ++r) {
      int py = py0 + 2 * wv + r;
      int px = px0 + m;
      size_t pix = (size_t)py * IMW + px;
      f32x4 v;
#pragma unroll
      for (int e = 0; e < 4; ++e) {
        float x = acc[g][r][e] + bb[e];
        if (LRELU) x = x >= 0.f ? x : 0.1f * x;
        v[e] = x;
      }
      if (RES == 1) {
        f32x4 rv = *(const f32x4*)&res[((size_t)z * HW + pix) * res_cst + g * 16 + q * 4];
#pragma unroll
        for (int e = 0; e < 4; ++e) v[e] += rv[e];
      }
      if (RES == 2) {
#pragma unroll
        for (int e = 0; e < 4; ++e)
          v[e] += res[((size_t)z * res_cst + res_coff + g * 16 + q * 4 + e) * HW + pix];
      }
      if (OUTMODE == 0 || OUTMODE == 3) {
        uint2 w;
        w.x = pk2(v[0], v[1]);
        w.y = pk2(v[2], v[3]);
        *(uint2*)&((us*)out)[((size_t)z * HW + pix) * out_cst + out_coff + g * 16 + q * 4] = w;
      }
      if (OUTMODE == 2)
        *(f32x4*)&((float*)out)[((size_t)z * HW + pix) * out_cst + g * 16 + q * 4] = v;
      if (OUTMODE == 3)
        *(f32x4*)&outB[((size_t)z * HW + pix) * 32 + g * 16 + q * 4] = v;
    }
  }
}

// ---------------------------------------------------------------------------
// Deformable attention. valp [6][HW][32] bf16; off [2][HW][96] bf16;
// aw [2][HW][48] f32; out attn [2][HW][32] bf16.
// ---------------------------------------------------------------------------
__global__ __launch_bounds__(256) void deform_attn(
    const us* __restrict__ valp, const us* __restrict__ off,
    const float* __restrict__ aw, us* __restrict__ outp) {
  int pix = blockIdx.x * 256 + threadIdx.x;
  int b = blockIdx.y;
  int px = pix & (IMW - 1), py = pix >> 8;
  float refx = ((float)px + 0.5f) * (1.0f / IMW);
  float refy = ((float)py + 0.5f) * (1.0f / IMH);

  ushortx8 o8[12];
  {
    const ushortx8* ob = (const ushortx8*)(off + ((size_t)b * HW + pix) * 96);
#pragma unroll
    for (int j = 0; j < 12; ++j) o8[j] = ob[j];
  }
  f32x4 a4[12];
  {
    const f32x4* ab = (const f32x4*)(aw + ((size_t)b * HW + pix) * 48);
#pragma unroll
    for (int j = 0; j < 12; ++j) a4[j] = ab[j];
  }

#pragma unroll
  for (int hh = 0; hh < 4; ++hh) {
    float wv[12];
    float mx = -1e30f;
#pragma unroll
    for (int lp = 0; lp < 12; ++lp) {
      int ci = hh * 12 + lp;
      wv[lp] = a4[ci >> 2][ci & 3];
      mx = fmaxf(mx, wv[lp]);
    }
    float s = 0.f;
#pragma unroll
    for (int lp = 0; lp < 12; ++lp) {
      wv[lp] = __expf(wv[lp] - mx);
      s += wv[lp];
    }
    float inv = 1.f / s;

    float acc[8] = {0.f, 0.f, 0.f, 0.f, 0.f, 0.f, 0.f, 0.f};
#pragma unroll 1
    for (int l = 0; l < 3; ++l) {
      const us* vbase = valp + ((size_t)(b * 3 + l) * HW) * 32 + hh * 8;
#pragma unroll
      for (int p = 0; p < 4; ++p) {
        int ch = hh * 24 + l * 8 + p * 2;
        float ox = u2f(o8[ch >> 3][ch & 7]);
        float oy = u2f(o8[(ch + 1) >> 3][(ch + 1) & 7]);
        float x = (refx + ox * (1.0f / IMW)) * (float)IMW - 0.5f;
        float y = (refy + oy * (1.0f / IMH)) * (float)IMH - 0.5f;
        float x0f = floorf(x), y0f = floorf(y);
        float lx = x - x0f, ly = y - y0f;
        int x0 = (int)x0f, y0 = (int)y0f;
        float a = wv[l * 4 + p] * inv;
        float cw[4] = {(1.f - lx) * (1.f - ly) * a, lx * (1.f - ly) * a,
                       (1.f - lx) * ly * a, lx * ly * a};
#pragma unroll
        for (int k = 0; k < 4; ++k) {
          int xi = x0 + (k & 1), yi = y0 + (k >> 1);
          if ((unsigned)xi < IMW && (unsigned)yi < IMH) {
            const ushortx8 u = *(const ushortx8*)(vbase + (size_t)(yi * IMW + xi) * 32);
            float wgt = cw[k];
#pragma unroll
            for (int dd = 0; dd < 8; ++dd) acc[dd] = fmaf(wgt, u2f(u[dd]), acc[dd]);
          }
        }
      }
    }
    ushortx8 sv;
#pragma unroll
    for (int dd = 0; dd < 8; ++dd) sv[dd] = f2bu(acc[dd]);
    *(ushortx8*)(outp + ((size_t)b * HW + pix) * 32 + hh * 8) = sv;
  }
}

// ---------------------------------------------------------------------------
// srcframe[:,1] fp32 NCHW -> out1b NHWC-64 ch32..63 (bf16)
// ---------------------------------------------------------------------------
__global__ __launch_bounds__(256) void copy_src(const float* __restrict__ src,
                                                unsigned* __restrict__ out1b) {
  int pix = blockIdx.x * 256 + threadIdx.x;
  int b = blockIdx.y;
  const float* s = src + ((size_t)(b * 3 + 1) * 32) * HW + pix;
  unsigned u[16];
#pragma unroll
  for (int j = 0; j < 16; ++j)
    u[j] = pk2(s[(size_t)(2 * j) * HW], s[(size_t)(2 * j + 1) * HW]);
  unsigned* d = out1b + ((size_t)b * HW + pix) * 32 + 16;
#pragma unroll
  for (int j = 0; j < 4; ++j) {
    uint4 w;
    w.x = u[4 * j]; w.y = u[4 * j + 1]; w.z = u[4 * j + 2]; w.w = u[4 * j + 3];
    *(uint4*)&d[4 * j] = w;
  }
}

// ---------------------------------------------------------------------------
// final 1x1 conv + lrelu: out2 NHWC-32 f32 -> d_out fp32 NCHW
// ---------------------------------------------------------------------------
__global__ __launch_bounds__(256) void conv1x1_fu(
    const float* __restrict__ in, const float* __restrict__ wgt,
    const float* __restrict__ bias, float* __restrict__ out) {
  int pix = blockIdx.x * 256 + threadIdx.x;
  int b = blockIdx.y;
  float vin[32];
  {
    const f32x4* s = (const f32x4*)(in + ((size_t)b * HW + pix) * 32);
#pragma unroll
    for (int j = 0; j < 8; ++j) {
      f32x4 v = s[j];
#pragma unroll
      for (int e = 0; e < 4; ++e) vin[4 * j + e] = v[e];
    }
  }
#pragma unroll 1
  for (int oc = 0; oc < 32; ++oc) {
    float a = bias[oc];
#pragma unroll
    for (int ci = 0; ci < 32; ++ci) a = fmaf(wgt[oc * 32 + ci], vin[ci], a);
    a = a >= 0.f ? a : 0.1f * a;
    out[((size_t)b * 32 + oc) * HW + pix] = a;
  }
}

// ---------------------------------------------------------------------------
extern "C" void kernel_launch(void* const* d_in, const int* in_sizes, int n_in,
                              void* d_out, int out_size, void* d_ws, size_t ws_size,
                              hipStream_t stream) {
  (void)in_sizes; (void)n_in; (void)out_size;
  // Footprint: 25,614,592 floats = 102.46 MB (same guard as round 4, known OK).
  if (ws_size < 25614592ull * 4) return;

  const float* frame = (const float*)d_in[0];
  const float* srcframe = (const float*)d_in[1];
  const float* flowf = (const float*)d_in[2];
  const float* flowb = (const float*)d_in[3];

  float* ws = (float*)d_ws;
  us* wsu = (us*)d_ws;

  // bf16 weights [tap][oc][KPAD], offsets in shorts (end 373,248 = 186,624 fl)
  static const int w2off[9] = {0,      110592, 193536, 202752, 285696,
                               327168, 336384, 345600, 364032};
  // Activation slots (float offsets):
  //  S1 @   186,624 (6,291,456): fnhwc -> offb -> ff1out
  //  S2 @ 6,478,080 (6,553,600): qk -> V -> awb(f32) -> out1b
  //  S3 @13,031,680 (6,291,456): Q -> attn + convout -> out2(f32)
  //  S4 @19,323,136 (6,291,456): Vp -> out1f(f32)
  us* fnhwc = (us*)(ws + 186624);
  unsigned* qk_u = (unsigned*)(ws + 6478080);
  us* qk = (us*)qk_u;
  us* Q = (us*)(ws + 13031680);
  us* V = (us*)(ws + 6478080);
  us* Vp = (us*)(ws + 19323136);
  us* offb = (us*)(ws + 186624);
  float* awb = (float*)(ws + 6478080);
  us* attn = (us*)(ws + 13031680);
  us* convout = (us*)(ws + 13031680 + 2097152);
  us* out1b = (us*)(ws + 6478080);
  unsigned* out1b_u = (unsigned*)out1b;
  float* out1f = (float*)(ws + 19323136);
  us* ff1out = (us*)(ws + 186624);
  float* out2 = (float*)(ws + 13031680);

  // 1) weight prep
  {
    PrepArgs pa;
    static const int srcidx[9] = {4, 6, 8, 10, 12, 14, 16, 18, 20};
    static const int OCs[9] = {96, 96, 32, 96, 48, 32, 32, 32, 32};
    static const int CINs[9] = {100, 96, 32, 96, 96, 32, 32, 64, 32};
    static const int KPADs[9] = {128, 96, 32, 96, 96, 32, 32, 64, 32};
    for (int i = 0; i < 9; ++i) {
      pa.src[i] = (const float*)d_in[srcidx[i]];
      pa.dst[i] = wsu + w2off[i];
      pa.OC[i] = OCs[i];
      pa.CIN[i] = CINs[i];
      pa.KPAD[i] = KPADs[i];
    }
    prep_weights<<<dim3(432, 9), 256, 0, stream>>>(pa);
  }

  // 2) frame -> NHWC bf16
  frame_to_nhwc<<<dim3(256, 2), 256, 0, stream>>>(frame, (unsigned*)fnhwc);

  // 3) qk_in NHWC-100
  build_qkin<<<dim3(256, 2), 256, 0, stream>>>(fnhwc, flowf, flowb, qk_u);

  dim3 cg2(16, 32, 2);

  // 4) qureys = lrelu(conv_qk)  100->96
  conv3x3_mfma<200, 100, 128, 1, 96, 1, 0, 0, 0, true><<<cg2, 256, 0, stream>>>(
      qk, wsu + w2off[0], (const float*)d_in[5], Q, 96, 0, nullptr, nullptr, 0, 0);

  // 5) value = conv_v(fnhwc) 96->96
  conv3x3_mfma<192, 96, 96, 1, 96, 1, 0, 0, 0, false><<<cg2, 256, 0, stream>>>(
      fnhwc, wsu + w2off[1], (const float*)d_in[7], V, 96, 0, nullptr, nullptr, 0, 0);

  // 6) val = conv_vp per (b,l) 32->32 -> Vp [6][HW][32]
  conv3x3_mfma<64, 96, 32, 1, 32, 3, 32, 0, 0, false><<<dim3(16, 32, 6), 256, 0, stream>>>(
      V, wsu + w2off[2], (const float*)d_in[9], Vp, 32, 0, nullptr, nullptr, 0, 0);

  // 7) off = conv_off(Q) 96->96 (S1; fnhwc dead)
  conv3x3_mfma<192, 96, 96, 1, 96, 1, 0, 0, 0, false><<<cg2, 256, 0, stream>>>(
      Q, wsu + w2off[3], (const float*)d_in[11], offb, 96, 0, nullptr, nullptr, 0, 0);

  // 8) aw = conv_aw(Q) 96->48 f32 NHWC (S2; V dead)
  conv3x3_mfma<192, 96, 96, 1, 48, 1, 0, 0, 2, false><<<cg2, 256, 0, stream>>>(
      Q, wsu + w2off[4], (const float*)d_in[13], awb, 48, 0, nullptr, nullptr, 0, 0);

  // 9) deformable attention -> attn (S3; Q dead)
  deform_attn<<<dim3(256, 2), 256, 0, stream>>>(Vp, offb, awb, attn);

  // 10) conv_out(attn) 32->32 (S3 tail)
  conv3x3_mfma<64, 32, 32, 1, 32, 1, 0, 0, 0, false><<<cg2, 256, 0, stream>>>(
      attn, wsu + w2off[5], (const float*)d_in[15], convout, 32, 0, nullptr, nullptr, 0, 0);

  // 11) out1 = conv_ffd(convout) + frame[:,1] -> out1b(NHWC-64 bf16) + out1f(f32)
  conv3x3_mfma<64, 32, 32, 1, 32, 1, 0, 2, 3, false><<<cg2, 256, 0, stream>>>(
      convout, wsu + w2off[6], (const float*)d_in[17], out1b, 64, 0, out1f, frame, 96, 32);

  // 12) srcframe[:,1] -> out1b ch32..63
  copy_src<<<dim3(256, 2), 256, 0, stream>>>(srcframe, out1b_u);

  // 13) ff1 = lrelu(conv dil=2 on out1b 64ch) -> ff1out (S1; offb dead)
  conv3x3_mfma<128, 64, 64, 2, 32, 1, 0, 0, 0, true><<<cg2, 256, 0, stream>>>(
      out1b, wsu + w2off[7], (const float*)d_in[19], ff1out, 32, 0, nullptr, nullptr, 0, 0);

  // 14) out2 = conv_ff2(ff1out) + out1f -> f32 NHWC-32 (S3; attn/convout dead)
  conv3x3_mfma<64, 32, 32, 1, 32, 1, 0, 1, 2, false><<<cg2, 256, 0, stream>>>(
      ff1out, wsu + w2off[8], (const float*)d_in[21], out2, 32, 0, nullptr, out1f, 32, 0);

  // 15) out = lrelu(conv_fu 1x1(out2)) -> fp32 NCHW d_out
  conv1x1_fu<<<dim3(256, 2), 256, 0, stream>>>(out2, (const float*)d_in[22],
                                               (const float*)d_in[23], (float*)d_out);
}

// Round 6
// 576.262 us; speedup vs baseline: 4.1718x; 1.2104x over previous
//
#include <hip/hip_runtime.h>
#include <hip/hip_bf16.h>

typedef __hip_bfloat16 bf16;
typedef unsigned short us;
typedef __attribute__((ext_vector_type(8))) short short8;
typedef __attribute__((ext_vector_type(8))) unsigned short ushortx8;
typedef __attribute__((ext_vector_type(4))) float f32x4;

#define HW 65536
#define IMW 256
#define IMH 256

static __device__ __forceinline__ float u2f(us u) {
  return __uint_as_float(((unsigned)u) << 16);
}
static __device__ __forceinline__ us f2bu(float x) {
  bf16 h = __float2bfloat16(x);
  return *reinterpret_cast<us*>(&h);
}
static __device__ __forceinline__ unsigned pk2(float a, float b) {
  return (unsigned)f2bu(a) | ((unsigned)f2bu(b) << 16);
}

// ---------------------------------------------------------------------------
// Weight prep: fp32 [oc][ci][3][3] -> bf16 [tap][oc][KPAD] (K zero-padded).
// ---------------------------------------------------------------------------
struct PrepArgs {
  const float* src[9];
  us* dst[9];
  int OC[9], CIN[9], KPAD[9];
};

__global__ __launch_bounds__(256) void prep_weights(PrepArgs a) {
  int j = blockIdx.y;
  int n = blockIdx.x * 256 + threadIdx.x;
  int OC = a.OC[j], CIN = a.CIN[j], KPAD = a.KPAD[j];
  int tot = 9 * OC * KPAD;
  if (n >= tot) return;
  int t = n / (OC * KPAD);
  int rem = n - t * OC * KPAD;
  int oc = rem / KPAD;
  int k = rem - oc * KPAD;
  float v = (k < CIN) ? a.src[j][(size_t)(oc * CIN + k) * 9 + t] : 0.f;
  a.dst[j][n] = f2bu(v);
}

// ---------------------------------------------------------------------------
// frame fp32 NCHW [b][96][HW] -> NHWC bf16 [b][HW][96]
// ---------------------------------------------------------------------------
__global__ __launch_bounds__(256) void frame_to_nhwc(const float* __restrict__ frame,
                                                     unsigned* __restrict__ fn) {
  int pix = blockIdx.x * 256 + threadIdx.x;
  int b = blockIdx.y;
  const float* s = frame + (size_t)b * 96 * HW + pix;
  unsigned u[48];
#pragma unroll
  for (int j = 0; j < 48; ++j)
    u[j] = pk2(s[(size_t)(2 * j) * HW], s[(size_t)(2 * j + 1) * HW]);
  unsigned* d = fn + ((size_t)b * HW + pix) * 48;
#pragma unroll
  for (int j = 0; j < 12; ++j) {
    uint4 w;
    w.x = u[4 * j]; w.y = u[4 * j + 1]; w.z = u[4 * j + 2]; w.w = u[4 * j + 3];
    *(uint4*)&d[4 * j] = w;
  }
}

// ---------------------------------------------------------------------------
// qk_in build from NHWC frame: warp01 | frame[:,1] | warp21 | flows
// -> qk NHWC bf16 [b][HW][100]
// ---------------------------------------------------------------------------
static __device__ void warp_nhwc(const us* __restrict__ fn, size_t bbase, int coff,
                                 float x, float y, unsigned* uo) {
  float x0f = floorf(x), y0f = floorf(y);
  float lx = x - x0f, ly = y - y0f;
  int x0 = (int)x0f, y0 = (int)y0f;
  float wt[4] = {(1.f - lx) * (1.f - ly), lx * (1.f - ly), (1.f - lx) * ly, lx * ly};
  float acc[32] = {};
#pragma unroll
  for (int k = 0; k < 4; ++k) {
    int xi = x0 + (k & 1), yi = y0 + (k >> 1);
    if ((unsigned)xi < IMW && (unsigned)yi < IMH) {
      const ushortx8* s =
          (const ushortx8*)(fn + (bbase + (size_t)yi * IMW + xi) * 96 + coff);
      float w = wt[k];
#pragma unroll
      for (int cj = 0; cj < 4; ++cj) {
        ushortx8 vv = s[cj];
#pragma unroll
        for (int e = 0; e < 8; ++e)
          acc[cj * 8 + e] = fmaf(w, u2f(vv[e]), acc[cj * 8 + e]);
      }
    }
  }
#pragma unroll
  for (int j = 0; j < 16; ++j) uo[j] = pk2(acc[2 * j], acc[2 * j + 1]);
}

__global__ __launch_bounds__(256) void build_qkin(
    const us* __restrict__ fn, const float* __restrict__ flowf,
    const float* __restrict__ flowb, unsigned* __restrict__ qk) {
  int pix = blockIdx.x * 256 + threadIdx.x;
  int b = blockIdx.y;
  int px = pix & 255, py = pix >> 8;

  float fbx = flowb[((size_t)(b * 2 + 0) * 2 + 0) * HW + pix];
  float fby = flowb[((size_t)(b * 2 + 0) * 2 + 1) * HW + pix];
  float ffx = flowf[((size_t)(b * 2 + 1) * 2 + 0) * HW + pix];
  float ffy = flowf[((size_t)(b * 2 + 1) * 2 + 1) * HW + pix];

  unsigned u[50];
  {
    const unsigned* s = (const unsigned*)(fn + ((size_t)b * HW + pix) * 96);
#pragma unroll
    for (int j = 0; j < 16; ++j) u[16 + j] = s[16 + j];
  }
  u[48] = pk2(ffx, ffy);
  u[49] = pk2(fbx, fby);

  warp_nhwc(fn, (size_t)b * HW, 0, (float)px + fbx, (float)py + fby, &u[0]);
  warp_nhwc(fn, (size_t)b * HW, 64, (float)px + ffx, (float)py + ffy, &u[32]);

  unsigned* qb = qk + ((size_t)b * HW + pix) * 50;
#pragma unroll
  for (int j = 0; j < 25; ++j) {
    uint2 t;
    t.x = u[2 * j];
    t.y = u[2 * j + 1];
    *(uint2*)(qb + 2 * j) = t;
  }
}

// ---------------------------------------------------------------------------
// MFMA implicit-GEMM 3x3 conv, NHWC bf16 input, K-chunked LDS staging.
// Block 256 thr = 4 waves = (2 g-halves) x (2 row-halves); tile 16x8 px.
// Each wave: 4 rows x ~G/2 oc-groups -> each A-frag (weights, global/L2)
// feeds 4 MFMAs; B-frags from LDS.
// CIN: real channels; CST: global cstride (shorts); KPAD: padded K (mult 32);
// KCH: K-chunk staged in LDS per barrier (mult 32).
// ZDIV/CSUB: z -> (bin=z/ZDIV, coff=(z%ZDIV)*CSUB).
// RES: 0 none, 1 f32 NHWC (res_cst), 2 fp32 NCHW (res_cst,res_coff).
// OUTMODE: 0 bf16 NHWC (out_cst,out_coff), 2 f32 NHWC, 3 = 0 + f32 NHWC-32.
// ---------------------------------------------------------------------------
template <int CIN, int CST, int KPAD, int KCH, int DIL, int G, int ZDIV, int CSUB,
          int RES, int OUTMODE, bool LRELU>
__global__ __launch_bounds__(256) void conv3x3_mfma(
    const us* __restrict__ in, const us* __restrict__ W2,
    const float* __restrict__ bias, void* __restrict__ out, int out_cst,
    int out_coff, float* __restrict__ outB, const float* __restrict__ res,
    int res_cst, int res_coff) {
  constexpr int OC = G * 16;
  constexpr int COLS = 16 + 2 * DIL;
  constexpr int ROWS = 8 + 2 * DIL;
  constexpr int HALO = ROWS * COLS;
  constexpr int CIPAD = KCH + 8;
  constexpr int CH = KCH / 8;
  constexpr int NST = KPAD / KCH;
  constexpr int GW0 = (G + 1) / 2;
  __shared__ alignas(16) short lds[HALO * CIPAD];

  const int z = blockIdx.z;
  const int bin = z / ZDIV;
  const int coff = (z % ZDIV) * CSUB;
  const int px0 = blockIdx.x * 16, py0 = blockIdx.y * 8;
  const int lane = threadIdx.x & 63;
  const int wv = threadIdx.x >> 6;
  const int m = lane & 15, q = lane >> 4;
  const int gh = wv & 1, rh = wv >> 1;
  const int goff = gh * GW0;

  f32x4 acc[GW0][4];
#pragma unroll
  for (int g = 0; g < GW0; ++g)
#pragma unroll
    for (int r = 0; r < 4; ++r) acc[g][r] = 0.f;

#pragma unroll 1
  for (int s = 0; s < NST; ++s) {
    // ---- stage K-chunk of NHWC tile into LDS [pos][ci] ----------------
    for (int c = threadIdx.x; c < HALO * CH; c += 256) {
      int p = c / CH, cb = c - p * CH;
      int row = p / COLS, col = p - row * COLS;
      int gy = py0 + row - DIL, gx = px0 + col - DIL;
      bool ok = ((unsigned)gy < IMH) && ((unsigned)gx < IMW);
      int ci0 = s * KCH + cb * 8;
      const us* gp = in + ((size_t)bin * HW + (size_t)gy * IMW + gx) * CST + coff + ci0;
      if (CIN == KPAD) {
        short8 v = (short8)0;
        if (ok) v = *(const short8*)gp;
        *(short8*)&lds[p * CIPAD + cb * 8] = v;
      } else {
        uint2 h0; h0.x = 0; h0.y = 0;
        uint2 h1; h1.x = 0; h1.y = 0;
        if (ok && ci0 + 4 <= CIN) h0 = *(const uint2*)gp;
        if (ok && ci0 + 8 <= CIN) h1 = *(const uint2*)(gp + 4);
        *(uint2*)&lds[p * CIPAD + cb * 8] = h0;
        *(uint2*)&lds[p * CIPAD + cb * 8 + 4] = h1;
      }
    }
    __syncthreads();

    // ---- MFMA over taps for this K-chunk ------------------------------
#pragma unroll
    for (int t = 0; t < 9; ++t) {
      const int dy = t / 3 - 1, dx = t - (t / 3) * 3 - 1;
#pragma unroll
      for (int kc = 0; kc < KCH / 32; ++kc) {
        short8 bfr[4];
#pragma unroll
        for (int r = 0; r < 4; ++r) {
          int rr = rh * 4 + r + DIL + dy * DIL;
          int cc = m + DIL + dx * DIL;
          bfr[r] = *(const short8*)&lds[(rr * COLS + cc) * CIPAD + kc * 32 + q * 8];
        }
#pragma unroll
        for (int g = 0; g < GW0; ++g) {
          if (goff + g < G) {
            short8 af = *(const short8*)(W2 +
                (size_t)(t * OC + (goff + g) * 16 + m) * KPAD + s * KCH + kc * 32 + q * 8);
#pragma unroll
            for (int r = 0; r < 4; ++r)
              acc[g][r] =
                  __builtin_amdgcn_mfma_f32_16x16x32_bf16(af, bfr[r], acc[g][r], 0, 0, 0);
          }
        }
      }
    }
    if (s + 1 < NST) __syncthreads();
  }

  // ---- epilogue -------------------------------------------------------
#pragma unroll
  for (int g = 0; g < GW0; ++g) {
    if (goff + g < G) {
      int oc0 = (goff + g) * 16 + q * 4;
      f32x4 bb = *(const f32x4*)&bias[oc0];
#pragma unroll
      for (int r = 0; r < 4; ++r) {
        int py = py0 + rh * 4 + r;
        int px = px0 + m;
        size_t pix = (size_t)py * IMW + px;
        f32x4 v;
#pragma unroll
        for (int e = 0; e < 4; ++e) {
          float x = acc[g][r][e] + bb[e];
          if (LRELU) x = x >= 0.f ? x : 0.1f * x;
          v[e] = x;
        }
        if (RES == 1) {
          f32x4 rv = *(const f32x4*)&res[((size_t)z * HW + pix) * res_cst + oc0];
#pragma unroll
          for (int e = 0; e < 4; ++e) v[e] += rv[e];
        }
        if (RES == 2) {
#pragma unroll
          for (int e = 0; e < 4; ++e)
            v[e] += res[((size_t)z * res_cst + res_coff + oc0 + e) * HW + pix];
        }
        if (OUTMODE == 0 || OUTMODE == 3) {
          uint2 w;
          w.x = pk2(v[0], v[1]);
          w.y = pk2(v[2], v[3]);
          *(uint2*)&((us*)out)[((size_t)z * HW + pix) * out_cst + out_coff + oc0] = w;
        }
        if (OUTMODE == 2)
          *(f32x4*)&((float*)out)[((size_t)z * HW + pix) * out_cst + oc0] = v;
        if (OUTMODE == 3)
          *(f32x4*)&outB[((size_t)z * HW + pix) * 32 + oc0] = v;
      }
    }
  }
}

// ---------------------------------------------------------------------------
// Deformable attention. valp [6][HW][32] bf16; off [2][HW][96] bf16;
// aw [2][HW][48] f32; out attn [2][HW][32] bf16.
// ---------------------------------------------------------------------------
__global__ __launch_bounds__(256) void deform_attn(
    const us* __restrict__ valp, const us* __restrict__ off,
    const float* __restrict__ aw, us* __restrict__ outp) {
  int pix = blockIdx.x * 256 + threadIdx.x;
  int b = blockIdx.y;
  int px = pix & (IMW - 1), py = pix >> 8;
  float refx = ((float)px + 0.5f) * (1.0f / IMW);
  float refy = ((float)py + 0.5f) * (1.0f / IMH);

  ushortx8 o8[12];
  {
    const ushortx8* ob = (const ushortx8*)(off + ((size_t)b * HW + pix) * 96);
#pragma unroll
    for (int j = 0; j < 12; ++j) o8[j] = ob[j];
  }
  f32x4 a4[12];
  {
    const f32x4* ab = (const f32x4*)(aw + ((size_t)b * HW + pix) * 48);
#pragma unroll
    for (int j = 0; j < 12; ++j) a4[j] = ab[j];
  }

#pragma unroll
  for (int hh = 0; hh < 4; ++hh) {
    float wv[12];
    float mx = -1e30f;
#pragma unroll
    for (int lp = 0; lp < 12; ++lp) {
      int ci = hh * 12 + lp;
      wv[lp] = a4[ci >> 2][ci & 3];
      mx = fmaxf(mx, wv[lp]);
    }
    float s = 0.f;
#pragma unroll
    for (int lp = 0; lp < 12; ++lp) {
      wv[lp] = __expf(wv[lp] - mx);
      s += wv[lp];
    }
    float inv = 1.f / s;

    float acc[8] = {0.f, 0.f, 0.f, 0.f, 0.f, 0.f, 0.f, 0.f};
#pragma unroll 1
    for (int l = 0; l < 3; ++l) {
      const us* vbase = valp + ((size_t)(b * 3 + l) * HW) * 32 + hh * 8;
#pragma unroll
      for (int p = 0; p < 4; ++p) {
        int ch = hh * 24 + l * 8 + p * 2;
        float ox = u2f(o8[ch >> 3][ch & 7]);
        float oy = u2f(o8[(ch + 1) >> 3][(ch + 1) & 7]);
        float x = (refx + ox * (1.0f / IMW)) * (float)IMW - 0.5f;
        float y = (refy + oy * (1.0f / IMH)) * (float)IMH - 0.5f;
        float x0f = floorf(x), y0f = floorf(y);
        float lx = x - x0f, ly = y - y0f;
        int x0 = (int)x0f, y0 = (int)y0f;
        float a = wv[l * 4 + p] * inv;
        float cw[4] = {(1.f - lx) * (1.f - ly) * a, lx * (1.f - ly) * a,
                       (1.f - lx) * ly * a, lx * ly * a};
#pragma unroll
        for (int k = 0; k < 4; ++k) {
          int xi = x0 + (k & 1), yi = y0 + (k >> 1);
          if ((unsigned)xi < IMW && (unsigned)yi < IMH) {
            const ushortx8 u = *(const ushortx8*)(vbase + (size_t)(yi * IMW + xi) * 32);
            float wgt = cw[k];
#pragma unroll
            for (int dd = 0; dd < 8; ++dd) acc[dd] = fmaf(wgt, u2f(u[dd]), acc[dd]);
          }
        }
      }
    }
    ushortx8 sv;
#pragma unroll
    for (int dd = 0; dd < 8; ++dd) sv[dd] = f2bu(acc[dd]);
    *(ushortx8*)(outp + ((size_t)b * HW + pix) * 32 + hh * 8) = sv;
  }
}

// ---------------------------------------------------------------------------
// srcframe[:,1] fp32 NCHW -> out1b NHWC-64 ch32..63 (bf16)
// ---------------------------------------------------------------------------
__global__ __launch_bounds__(256) void copy_src(const float* __restrict__ src,
                                                unsigned* __restrict__ out1b) {
  int pix = blockIdx.x * 256 + threadIdx.x;
  int b = blockIdx.y;
  const float* s = src + ((size_t)(b * 3 + 1) * 32) * HW + pix;
  unsigned u[16];
#pragma unroll
  for (int j = 0; j < 16; ++j)
    u[j] = pk2(s[(size_t)(2 * j) * HW], s[(size_t)(2 * j + 1) * HW]);
  unsigned* d = out1b + ((size_t)b * HW + pix) * 32 + 16;
#pragma unroll
  for (int j = 0; j < 4; ++j) {
    uint4 w;
    w.x = u[4 * j]; w.y = u[4 * j + 1]; w.z = u[4 * j + 2]; w.w = u[4 * j + 3];
    *(uint4*)&d[4 * j] = w;
  }
}

// ---------------------------------------------------------------------------
// final 1x1 conv + lrelu: out2 NHWC-32 f32 -> d_out fp32 NCHW
// ---------------------------------------------------------------------------
__global__ __launch_bounds__(256) void conv1x1_fu(
    const float* __restrict__ in, const float* __restrict__ wgt,
    const float* __restrict__ bias, float* __restrict__ out) {
  int pix = blockIdx.x * 256 + threadIdx.x;
  int b = blockIdx.y;
  float vin[32];
  {
    const f32x4* s = (const f32x4*)(in + ((size_t)b * HW + pix) * 32);
#pragma unroll
    for (int j = 0; j < 8; ++j) {
      f32x4 v = s[j];
#pragma unroll
      for (int e = 0; e < 4; ++e) vin[4 * j + e] = v[e];
    }
  }
#pragma unroll 1
  for (int oc = 0; oc < 32; ++oc) {
    float a = bias[oc];
#pragma unroll
    for (int ci = 0; ci < 32; ++ci) a = fmaf(wgt[oc * 32 + ci], vin[ci], a);
    a = a >= 0.f ? a : 0.1f * a;
    out[((size_t)b * 32 + oc) * HW + pix] = a;
  }
}

// ---------------------------------------------------------------------------
extern "C" void kernel_launch(void* const* d_in, const int* in_sizes, int n_in,
                              void* d_out, int out_size, void* d_ws, size_t ws_size,
                              hipStream_t stream) {
  (void)in_sizes; (void)n_in; (void)out_size;
  // Footprint: 25,614,592 floats = 102.46 MB (same as rounds 4-5, known OK).
  if (ws_size < 25614592ull * 4) return;

  const float* frame = (const float*)d_in[0];
  const float* srcframe = (const float*)d_in[1];
  const float* flowf = (const float*)d_in[2];
  const float* flowb = (const float*)d_in[3];

  float* ws = (float*)d_ws;
  us* wsu = (us*)d_ws;

  // bf16 weights [tap][oc][KPAD], offsets in shorts (end 373,248 = 186,624 fl)
  static const int w2off[9] = {0,      110592, 193536, 202752, 285696,
                               327168, 336384, 345600, 364032};
  // Activation slots (float offsets):
  //  S1 @   186,624 (6,291,456): fnhwc -> offb -> ff1out
  //  S2 @ 6,478,080 (6,553,600): qk -> V -> awb(f32) -> out1b
  //  S3 @13,031,680 (6,291,456): Q -> attn + convout -> out2(f32)
  //  S4 @19,323,136 (6,291,456): Vp -> out1f(f32)
  us* fnhwc = (us*)(ws + 186624);
  unsigned* qk_u = (unsigned*)(ws + 6478080);
  us* qk = (us*)qk_u;
  us* Q = (us*)(ws + 13031680);
  us* V = (us*)(ws + 6478080);
  us* Vp = (us*)(ws + 19323136);
  us* offb = (us*)(ws + 186624);
  float* awb = (float*)(ws + 6478080);
  us* attn = (us*)(ws + 13031680);
  us* convout = (us*)(ws + 13031680 + 2097152);
  us* out1b = (us*)(ws + 6478080);
  unsigned* out1b_u = (unsigned*)out1b;
  float* out1f = (float*)(ws + 19323136);
  us* ff1out = (us*)(ws + 186624);
  float* out2 = (float*)(ws + 13031680);

  // 1) weight prep
  {
    PrepArgs pa;
    static const int srcidx[9] = {4, 6, 8, 10, 12, 14, 16, 18, 20};
    static const int OCs[9] = {96, 96, 32, 96, 48, 32, 32, 32, 32};
    static const int CINs[9] = {100, 96, 32, 96, 96, 32, 32, 64, 32};
    static const int KPADs[9] = {128, 96, 32, 96, 96, 32, 32, 64, 32};
    for (int i = 0; i < 9; ++i) {
      pa.src[i] = (const float*)d_in[srcidx[i]];
      pa.dst[i] = wsu + w2off[i];
      pa.OC[i] = OCs[i];
      pa.CIN[i] = CINs[i];
      pa.KPAD[i] = KPADs[i];
    }
    prep_weights<<<dim3(432, 9), 256, 0, stream>>>(pa);
  }

  // 2) frame -> NHWC bf16
  frame_to_nhwc<<<dim3(256, 2), 256, 0, stream>>>(frame, (unsigned*)fnhwc);

  // 3) qk_in NHWC-100
  build_qkin<<<dim3(256, 2), 256, 0, stream>>>(fnhwc, flowf, flowb, qk_u);

  dim3 cg2(16, 32, 2);

  // 4) qureys = lrelu(conv_qk)  100->96  (KPAD=128, KCH=64, G=6)
  conv3x3_mfma<100, 100, 128, 64, 1, 6, 1, 0, 0, 0, true><<<cg2, 256, 0, stream>>>(
      qk, wsu + w2off[0], (const float*)d_in[5], Q, 96, 0, nullptr, nullptr, 0, 0);

  // 5) value = conv_v(fnhwc) 96->96  (KCH=32)
  conv3x3_mfma<96, 96, 96, 32, 1, 6, 1, 0, 0, 0, false><<<cg2, 256, 0, stream>>>(
      fnhwc, wsu + w2off[1], (const float*)d_in[7], V, 96, 0, nullptr, nullptr, 0, 0);

  // 6) val = conv_vp per (b,l) 32->32 -> Vp [6][HW][32]
  conv3x3_mfma<32, 96, 32, 32, 1, 2, 3, 32, 0, 0, false><<<dim3(16, 32, 6), 256, 0, stream>>>(
      V, wsu + w2off[2], (const float*)d_in[9], Vp, 32, 0, nullptr, nullptr, 0, 0);

  // 7) off = conv_off(Q) 96->96 (S1; fnhwc dead)
  conv3x3_mfma<96, 96, 96, 32, 1, 6, 1, 0, 0, 0, false><<<cg2, 256, 0, stream>>>(
      Q, wsu + w2off[3], (const float*)d_in[11], offb, 96, 0, nullptr, nullptr, 0, 0);

  // 8) aw = conv_aw(Q) 96->48 f32 NHWC (S2; V dead)  G=3
  conv3x3_mfma<96, 96, 96, 32, 1, 3, 1, 0, 0, 2, false><<<cg2, 256, 0, stream>>>(
      Q, wsu + w2off[4], (const float*)d_in[13], awb, 48, 0, nullptr, nullptr, 0, 0);

  // 9) deformable attention -> attn (S3; Q dead)
  deform_attn<<<dim3(256, 2), 256, 0, stream>>>(Vp, offb, awb, attn);

  // 10) conv_out(attn) 32->32 (S3 tail)
  conv3x3_mfma<32, 32, 32, 32, 1, 2, 1, 0, 0, 0, false><<<cg2, 256, 0, stream>>>(
      attn, wsu + w2off[5], (const float*)d_in[15], convout, 32, 0, nullptr, nullptr, 0, 0);

  // 11) out1 = conv_ffd(convout) + frame[:,1] -> out1b(NHWC-64 bf16) + out1f(f32)
  conv3x3_mfma<32, 32, 32, 32, 1, 2, 1, 0, 2, 3, false><<<cg2, 256, 0, stream>>>(
      convout, wsu + w2off[6], (const float*)d_in[17], out1b, 64, 0, out1f, frame, 96, 32);

  // 12) srcframe[:,1] -> out1b ch32..63
  copy_src<<<dim3(256, 2), 256, 0, stream>>>(srcframe, out1b_u);

  // 13) ff1 = lrelu(conv dil=2 on out1b 64ch) -> ff1out (S1; offb dead)
  conv3x3_mfma<64, 64, 64, 32, 2, 2, 1, 0, 0, 0, true><<<cg2, 256, 0, stream>>>(
      out1b, wsu + w2off[7], (const float*)d_in[19], ff1out, 32, 0, nullptr, nullptr, 0, 0);

  // 14) out2 = conv_ff2(ff1out) + out1f -> f32 NHWC-32 (S3; attn/convout dead)
  conv3x3_mfma<32, 32, 32, 32, 1, 2, 1, 0, 1, 2, false><<<cg2, 256, 0, stream>>>(
      ff1out, wsu + w2off[8], (const float*)d_in[21], out2, 32, 0, nullptr, out1f, 32, 0);

  // 15) out = lrelu(conv_fu 1x1(out2)) -> fp32 NCHW d_out
  conv1x1_fu<<<dim3(256, 2), 256, 0, stream>>>(out2, (const float*)d_in[22],
                                               (const float*)d_in[23], (float*)d_out);
}